// Round 10
// baseline (160.239 us; speedup 1.0000x reference)
//
#include <hip/hip_runtime.h>
#include <hip/hip_fp16.h>

// Tree NN: reps = emb[tokens] (4096 x 128 x 128); 7x: reps = tanh(concat(pairs) @ W_tree^T + b);
// out = root @ W_cls^T + b_cls.
//
// R10: occupancy 3 -> 4 blocks/CU by deleting bufB. Levels run IN-PLACE in bufA with a
// disjoint row rotation: gather->rows 0-63; L0 reads 0-63 / writes 0-31 (read-write overlap
// -> split barrier between MFMA-read and store, holding 32 packed fp16 = 16 VGPR); L1
// 0-31 -> 32-47; L2 32-47 -> 0-7; L3 0-7 -> bufC stash. Pair-batching extended one level
// deeper (stash after L3; batched L4/L5/L6): the pair-contig store row=(node>>1) keeps
// samples in disjoint row ranges automatically. LDS 53.2 -> 38.1 KB -> 4 blocks/CU
// (grid 1024, launch_bounds(256,4)). MFMA/wave/pair 320->304; barriers 14->15.
// Tripwire: WRITE_SIZE in tens of MB = L0-split spill -> revert.
//
// Wave w owns output n-tiles {2w,2w+1} at every level (Wf[2][8] = 64 VGPR of W-fragments).
// fp16 MFMA 16x16x32 (K-split 2 independent 4-chains at MT=1), fp32 accumulate/tanh/cls.
// Garbage rows at deep levels read stale-but-finite tanh outputs; masked at store.

typedef _Float16 half8 __attribute__((ext_vector_type(8)));
typedef float floatx4 __attribute__((ext_vector_type(4)));

#define STRIDE 264   // 256 + 8 fp16 pad: A-row ds_read_b128 conflict-free
#define NPAIR 2048

__device__ __forceinline__ float fast_tanh(float x) {
  // No clamp needed: e=inf -> 1; e=0 -> -1. Inputs never NaN.
  float e = __expf(2.f * x);
  return 1.f - 2.f * __builtin_amdgcn_rcpf(e + 1.f);
}

__device__ __forceinline__ unsigned pkrtz(float a, float b) {
  auto h = __builtin_amdgcn_cvt_pkrtz(a, b);   // __fp16 ext_vector(2)
  return __builtin_bit_cast(unsigned, h);
}

// K=256 MFMA for one 16-row m-tile, 2 n-tiles, K-split into 2 independent 4-chains.
// A-frag: A[m=lane&15][k=quad*8+j]; B-frag: B[k=quad*8+j][n=lane&15];
// D: col=lane&15, row=quad*4+reg (verified layouts, learn_hip m89/m91).
__device__ __forceinline__ void mfma_k256(const _Float16* arow, const half8 (&Wf)[2][8],
                                          floatx4 (&accO)[2]) {
  floatx4 aA[2], aB[2];
  aA[0] = (floatx4){0.f, 0.f, 0.f, 0.f}; aA[1] = (floatx4){0.f, 0.f, 0.f, 0.f};
  aB[0] = (floatx4){0.f, 0.f, 0.f, 0.f}; aB[1] = (floatx4){0.f, 0.f, 0.f, 0.f};
#pragma unroll
  for (int ks = 0; ks < 4; ++ks) {
    half8 x0 = *(const half8*)(arow + ks * 32);
    half8 x1 = *(const half8*)(arow + (ks + 4) * 32);
    aA[0] = __builtin_amdgcn_mfma_f32_16x16x32_f16(x0, Wf[0][ks],     aA[0], 0, 0, 0);
    aB[0] = __builtin_amdgcn_mfma_f32_16x16x32_f16(x1, Wf[0][ks + 4], aB[0], 0, 0, 0);
    aA[1] = __builtin_amdgcn_mfma_f32_16x16x32_f16(x0, Wf[1][ks],     aA[1], 0, 0, 0);
    aB[1] = __builtin_amdgcn_mfma_f32_16x16x32_f16(x1, Wf[1][ks + 4], aB[1], 0, 0, 0);
  }
  accO[0] = aA[0] + aB[0];
  accO[1] = aA[1] + aB[1];
}

// Generic level: read MT m-tiles at row INROW of inb, store tanh'd nodes (node<MOUT) to
// outb at row OUTROW+(node>>1), half (node&1). SPLIT: barrier between reads and stores
// (required when output rows overlap the level's read set -- L0). CLAMP8: clamp read row
// to <8 (bufC is 8 rows tall; garbage rows masked by MOUT at store).
template<int MT, int MOUT, int INROW, int OUTROW, bool SPLIT, bool CLAMP8>
__device__ __forceinline__ void level_ip(
    const _Float16* inb, _Float16* outb,
    const half8 (&Wf)[2][8], const float (&bias)[2],
    int nbase, int l15, int quad)
{
  floatx4 acc[MT][2];
  if (MT == 1) {
    const int rr = CLAMP8 ? (l15 < 8 ? l15 : 7) : l15;
    mfma_k256(inb + (INROW + rr) * STRIDE + quad * 8, Wf, acc[0]);
  } else {
#pragma unroll
    for (int m = 0; m < MT; ++m) {
      acc[m][0] = (floatx4){0.f, 0.f, 0.f, 0.f};
      acc[m][1] = (floatx4){0.f, 0.f, 0.f, 0.f};
    }
#pragma unroll
    for (int m = 0; m < MT; ++m) {
      const _Float16* arow = inb + (INROW + m * 16 + l15) * STRIDE + quad * 8;
#pragma unroll
      for (int ks = 0; ks < 8; ++ks) {
        half8 a = *(const half8*)(arow + ks * 32);
        acc[m][0] = __builtin_amdgcn_mfma_f32_16x16x32_f16(a, Wf[0][ks], acc[m][0], 0, 0, 0);
        acc[m][1] = __builtin_amdgcn_mfma_f32_16x16x32_f16(a, Wf[1][ks], acc[m][1], 0, 0, 0);
      }
    }
  }

  // tanh + fp16 pack BEFORE the split barrier: only MT*2*4 halves live across it.
  _Float16 hv[MT][2][4];
  const int mrow = quad * 4;
#pragma unroll
  for (int m = 0; m < MT; ++m)
#pragma unroll
    for (int i = 0; i < 2; ++i)
#pragma unroll
      for (int r = 0; r < 4; ++r) {
        const int node = m * 16 + mrow + r;
        if (node < MOUT) hv[m][i][r] = (_Float16)fast_tanh(acc[m][i][r] + bias[i]);
      }

  if (SPLIT) __syncthreads();

#pragma unroll
  for (int m = 0; m < MT; ++m)
#pragma unroll
    for (int i = 0; i < 2; ++i) {
      const int col = (nbase + i) * 16 + l15;
#pragma unroll
      for (int r = 0; r < 4; ++r) {
        const int node = m * 16 + mrow + r;
        if (node < MOUT)
          outb[(OUTROW + (node >> 1)) * STRIDE + (node & 1) * 128 + col] = hv[m][i][r];
      }
    }
}

__global__ __launch_bounds__(256, 4)
void tree_kernel(const int* __restrict__ tokens,
                 const float* __restrict__ embedding,
                 const float* __restrict__ W_tree,
                 const float* __restrict__ b_tree,
                 const float* __restrict__ W_cls,
                 const float* __restrict__ b_cls,
                 float* __restrict__ out)
{
  __shared__ __align__(16) _Float16 bufA[64 * STRIDE];   // leaves + all in-place levels (33.8 KB)
  __shared__ __align__(16) _Float16 bufC[8 * STRIDE];    // pair stash: L3 outs (4.2 KB)
  __shared__ float wavepart[4][2][3];                    // classifier partials (96 B)

  const int tid  = threadIdx.x;
  const int wid  = tid >> 6;
  const int lane = tid & 63;
  const int l15  = lane & 15;
  const int quad = lane >> 4;
  const int nbase = wid * 2;               // this wave's n-tile base (features [32*wid,32*wid+32))

  // ---- stage this wave's 2 n-tiles of W_tree as B-fragments (64 VGPR) ----
  // B[k][n] = W_tree[e=n][h=k]  (einsum 'bnh,eh->bne' => out = comb @ W^T)
  half8 Wf[2][8];
#pragma unroll
  for (int i = 0; i < 2; ++i) {
    const int e = (nbase + i) * 16 + l15;
#pragma unroll
    for (int ks = 0; ks < 8; ++ks) {
      const int k = ks * 32 + quad * 8;
      const float4* p = (const float4*)(W_tree + e * 256 + k);
      float4 lo = p[0], hi = p[1];
      half8 f;
      f[0] = (_Float16)lo.x; f[1] = (_Float16)lo.y; f[2] = (_Float16)lo.z; f[3] = (_Float16)lo.w;
      f[4] = (_Float16)hi.x; f[5] = (_Float16)hi.y; f[6] = (_Float16)hi.z; f[7] = (_Float16)hi.w;
      Wf[i][ks] = f;
    }
  }
  float bias[2];
#pragma unroll
  for (int i = 0; i < 2; ++i) bias[i] = b_tree[(nbase + i) * 16 + l15];

  // classifier weights for this lane's 2 columns: loop-invariant (6 VGPR)
  float wc[2][3];
#pragma unroll
  for (int i = 0; i < 2; ++i) {
    const int col = (nbase + i) * 16 + l15;
#pragma unroll
    for (int o = 0; o < 3; ++o) wc[i][o] = W_cls[o * 128 + col];
  }

  const int leaf = tid >> 1;               // 0..127
  const int hh   = tid & 1;                // which 64-feature half of the row

#pragma unroll 1
  for (int p = blockIdx.x; p < NPAIR; p += gridDim.x) {

    // ---- phase 1 per sample: gather + L0..L3 in-place, stash L3-out in bufC ----
#pragma unroll 1
    for (int j = 0; j < 2; ++j) {
      const int s = 2 * p + j;
      {
        const int tok = tokens[s * 128 + leaf];
        const float4* src = (const float4*)(embedding + (size_t)tok * 128 + hh * 64);
        uint4* dst = (uint4*)bufA + (leaf >> 1) * 33 + (leaf & 1) * 16 + hh * 8;
#pragma unroll
        for (int jj = 0; jj < 8; ++jj) {
          float4 x = src[2 * jj], y = src[2 * jj + 1];
          uint4 w;
          w.x = pkrtz(x.x, x.y); w.y = pkrtz(x.z, x.w);
          w.z = pkrtz(y.x, y.y); w.w = pkrtz(y.z, y.w);
          dst[jj] = w;                     // ds_write_b128
        }
      }
      __syncthreads();
      // L0: rows 0-63 -> 0-31 (in-place overlap: SPLIT barrier inside)
      level_ip<4, 64, 0,  0, true,  false>(bufA, bufA, Wf, bias, nbase, l15, quad);
      __syncthreads();
      // L1: rows 0-31 -> 32-47
      level_ip<2, 32, 0, 32, false, false>(bufA, bufA, Wf, bias, nbase, l15, quad);
      __syncthreads();
      // L2: rows 32-47 -> 0-7
      level_ip<1, 16, 32, 0, false, false>(bufA, bufA, Wf, bias, nbase, l15, quad);
      __syncthreads();
      // L3: rows 0-7 -> bufC rows [4j, 4j+4)  (rows 8-15 garbage, masked by MOUT=8)
      level_ip<1,  8, 0,  0, false, false>(bufA, bufC + j * 4 * STRIDE, Wf, bias, nbase, l15, quad);
      __syncthreads();
    }

    // ---- batched L4: bufC rows 0-7 (s0: 0-3, s1: 4-7) -> bufA rows 0-3 ----
    level_ip<1, 8, 0, 0, false, true>(bufC, bufA, Wf, bias, nbase, l15, quad);
    __syncthreads();
    // ---- batched L5: bufA rows 0-3 -> rows 4-5 (s0: 4, s1: 5) ----
    level_ip<1, 4, 0, 4, false, false>(bufA, bufA, Wf, bias, nbase, l15, quad);
    __syncthreads();

    // ---- batched L6 + classifier partials from registers ----
    {
      floatx4 acc[2];
      mfma_k256(bufA + (4 + l15) * STRIDE + quad * 8, Wf, acc);  // m-rows 0,1 = roots s0,s1
      float part[2][3] = {{0.f, 0.f, 0.f}, {0.f, 0.f, 0.f}};
      if (quad == 0) {
#pragma unroll
        for (int i = 0; i < 2; ++i) {
#pragma unroll
          for (int rr = 0; rr < 2; ++rr) {           // rr = sample
            float v = fast_tanh(acc[i][rr] + bias[i]);
#pragma unroll
            for (int o = 0; o < 3; ++o) part[rr][o] = fmaf(v, wc[i][o], part[rr][o]);
          }
        }
      }
#pragma unroll
      for (int rr = 0; rr < 2; ++rr) {
#pragma unroll
        for (int o = 0; o < 3; ++o) {
          float v = part[rr][o];                     // nonzero only in quad-0 lanes
          v += __shfl_down(v, 8);
          v += __shfl_down(v, 4);
          v += __shfl_down(v, 2);
          v += __shfl_down(v, 1);
          if (lane == 0) wavepart[wid][rr][o] = v;
        }
      }
    }
    __syncthreads();
    if (tid < 6) {
      const int rr = tid / 3, o = tid - 3 * rr;
      float v = wavepart[0][rr][o] + wavepart[1][rr][o]
              + wavepart[2][rr][o] + wavepart[3][rr][o];
      out[(2 * p + rr) * 3 + o] = v + b_cls[o];
    }
    // next pair's gather overwrites bufA: all L6 bufA reads completed before the wavepart
    // barrier; wavepart next written 12+ barriers later -> safe.
  }
}

extern "C" void kernel_launch(void* const* d_in, const int* in_sizes, int n_in,
                              void* d_out, int out_size, void* d_ws, size_t ws_size,
                              hipStream_t stream) {
  const int*   tokens    = (const int*)d_in[0];
  const float* embedding = (const float*)d_in[1];
  const float* W_tree    = (const float*)d_in[2];
  const float* b_tree    = (const float*)d_in[3];
  const float* W_cls     = (const float*)d_in[4];
  const float* b_cls     = (const float*)d_in[5];
  float* out = (float*)d_out;

  dim3 grid(1024), block(256);   // 4 blocks/CU x 256 CUs; 2 pairs per block
  tree_kernel<<<grid, block, 0, stream>>>(tokens, embedding, W_tree, b_tree, W_cls, b_cls, out);
}